// Round 7
// baseline (211.736 us; speedup 1.0000x reference)
//
#include <hip/hip_runtime.h>
#include <math.h>

// TimeEmbedding: out[b][i] = sin(t[b]*f_i) if i even else cos(t[b]*f_i),
// f_i = 10000^(-i/256), B=524288, D=512, f32 out (1 GiB). Write-BW-bound.
//
// R7 = R6 EXCEPT nontemporal stores (single-variable A/B).
//  Matrix so far: nt@depth2=220, plain@depth2=209, plain@depth>=16=200-204.
//  Untested cell: nt@depth63. Mechanism: nt bypasses L2 dirty-allocate ->
//  single hop to MALL/DRAM; its ack-latency penalty (seen at depth 2)
//  should vanish with a deep store queue.
//  - 256 blocks x 256 thr = 1024 waves; wave owns 512 consecutive rows.
//  - per 64-row segment: ONE per-lane coalesced t-load (prefetched a
//    segment ahead); per-row t broadcast via v_readlane (no memory op).
//  - 8 frequencies per lane loop-invariant (8 exp2 total per thread).

#define D_MODEL 512

typedef float f32x4 __attribute__((ext_vector_type(4)));

__device__ __forceinline__ float sin_rev(float r) {
    return __builtin_amdgcn_sinf(__builtin_amdgcn_fractf(r));  // HW sin takes revolutions
}
__device__ __forceinline__ float cos_rev(float r) {
    return __builtin_amdgcn_cosf(__builtin_amdgcn_fractf(r));
}

__global__ __launch_bounds__(256) void time_embed_kernel(
    const float* __restrict__ t, f32x4* __restrict__ out, int n_rows) {
    const int g = blockIdx.x * 256 + threadIdx.x;
    const int lane = threadIdx.x & 63;       // float4 slot within row
    const int w = g >> 6;                    // wave id
    const int nw = (gridDim.x * 256) >> 6;   // 1024 waves

    const float LOG2_10000_OVER_256 = 0.051904345232615426f; // log2(10000)/256
    const float INV_2PI = 0.15915494309189535f;

    float fa[4], fb[4];
#pragma unroll
    for (int j = 0; j < 4; ++j) {
        fa[j] = __builtin_amdgcn_exp2f(-(float)(4 * lane + j) * LOG2_10000_OVER_256) * INV_2PI;
        fb[j] = __builtin_amdgcn_exp2f(-(float)(4 * lane + 256 + j) * LOG2_10000_OVER_256) * INV_2PI;
    }

    const int rows_per_wave = n_rows / nw;   // 512
    const int row0 = w * rows_per_wave;
    if (row0 >= n_rows) return;
    const float* tw = t + row0;
    f32x4* outw = out + (size_t)row0 * (D_MODEL / 4);

    const int nseg = rows_per_wave >> 6;     // 8 segments of 64 rows
    float tl = tw[lane];                     // segment 0: one t per lane
    for (int seg = 0; seg < nseg; ++seg) {
        const int segn = (seg + 1 < nseg) ? (seg + 1) : seg;
        const float tln = tw[segn * 64 + lane];  // prefetch next segment's t

        f32x4* sp = outw + (size_t)seg * 64 * (D_MODEL / 4);
        for (int r8 = 0; r8 < 8; ++r8) {         // 8 rows per unrolled body
#pragma unroll
            for (int j = 0; j < 8; ++j) {
                // wave-uniform broadcast of this row's t (no memory op)
                const float tv = __int_as_float(
                    __builtin_amdgcn_readlane(__float_as_int(tl), r8 * 8 + j));
                f32x4 oa, ob;
                oa.x = sin_rev(tv * fa[0]);  // even col -> sin
                oa.y = cos_rev(tv * fa[1]);  // odd col  -> cos
                oa.z = sin_rev(tv * fa[2]);
                oa.w = cos_rev(tv * fa[3]);
                ob.x = sin_rev(tv * fb[0]);
                ob.y = cos_rev(tv * fb[1]);
                ob.z = sin_rev(tv * fb[2]);
                ob.w = cos_rev(tv * fb[3]);
                f32x4* rowp = sp + (size_t)(r8 * 8 + j) * (D_MODEL / 4);
                __builtin_nontemporal_store(oa, rowp + lane);       // 1KB wave-store, nt
                __builtin_nontemporal_store(ob, rowp + 64 + lane);  // 1KB wave-store, nt
            }
        }
        tl = tln;
    }
}

extern "C" void kernel_launch(void* const* d_in, const int* in_sizes, int n_in,
                              void* d_out, int out_size, void* d_ws, size_t ws_size,
                              hipStream_t stream) {
    const float* t = (const float*)d_in[0];
    f32x4* out = (f32x4*)d_out;
    const int n_rows = in_sizes[0];  // 524288 = 1024 waves * 512 rows
    time_embed_kernel<<<dim3(256), dim3(256), 0, stream>>>(t, out, n_rows);
}

// Round 8
// 200.582 us; speedup vs baseline: 1.0556x; 1.0556x over previous
//
#include <hip/hip_runtime.h>
#include <math.h>

// TimeEmbedding: out[b][i] = sin(t[b]*f_i) if i even else cos(t[b]*f_i),
// f_i = 10000^(-i/256), B=524288, D=512, f32 out (1 GiB). Write-BW-bound.
//
// FINAL (= R6, best of the ladder: 200.2 µs ≈ 5.4 TB/s sustained writes).
// Ladder summary (single-variable steps, all refchecked absmax=7.8e-3):
//   R0 naive thread/elem + consume-load        228.4
//   R1 nt + wave/row + prefetch-1              220.1   (nt hurts: +ack latency)
//   R3 plain + chunked + depth16               201.7   (deep store queue is the lever)
//   R4 plain + dense front                     209.1   (dense front theory refuted)
//   R5 plain + chunked + depth32               204.3   (flat)
//   R6 plain + 1024 waves + zero-load loop     200.2   <- this kernel
//   R7 R6 + nt                                 211.7   (nt harmful at all depths)
// Micro-model: in-order vmcnt retirement means any in-loop load consumed
// N VMEM-ops after issue caps outstanding stores at N; keep the steady-state
// loop free of loads (readlane broadcast) and depth >= 16. Beyond that the
// limit is the HBM write path (fill kernel's own 6.5 TB/s at 4x payload
// amortizes its ramp 3.3x better; every CU-side axis is flat +-2%).
//
//  - 256 blocks x 256 thr = 1024 waves (1/SIMD, 4/CU); wave owns 512
//    consecutive rows (1 MB private stream).
//  - per 64-row segment: ONE per-lane coalesced t-load (prefetched a
//    segment ahead); per-row t broadcast via v_readlane (no memory op)
//    -> steady-state loop is stores+VALU only, no vmcnt coupling.
//  - plain write-back dwordx4 stores, 2x contiguous 1KB per row.
//  - 8 frequencies per lane loop-invariant (8 exp2 total per thread);
//    freq folded by 1/(2pi) so HW v_fract+v_sin/v_cos (revolution domain)
//    do the range reduction; t in [0,1000] keeps f32 arg error ~1e-4.

#define D_MODEL 512

typedef float f32x4 __attribute__((ext_vector_type(4)));

__device__ __forceinline__ float sin_rev(float r) {
    return __builtin_amdgcn_sinf(__builtin_amdgcn_fractf(r));  // HW sin takes revolutions
}
__device__ __forceinline__ float cos_rev(float r) {
    return __builtin_amdgcn_cosf(__builtin_amdgcn_fractf(r));
}

__global__ __launch_bounds__(256) void time_embed_kernel(
    const float* __restrict__ t, f32x4* __restrict__ out, int n_rows) {
    const int g = blockIdx.x * 256 + threadIdx.x;
    const int lane = threadIdx.x & 63;       // float4 slot within row
    const int w = g >> 6;                    // wave id
    const int nw = (gridDim.x * 256) >> 6;   // 1024 waves

    const float LOG2_10000_OVER_256 = 0.051904345232615426f; // log2(10000)/256
    const float INV_2PI = 0.15915494309189535f;

    float fa[4], fb[4];
#pragma unroll
    for (int j = 0; j < 4; ++j) {
        fa[j] = __builtin_amdgcn_exp2f(-(float)(4 * lane + j) * LOG2_10000_OVER_256) * INV_2PI;
        fb[j] = __builtin_amdgcn_exp2f(-(float)(4 * lane + 256 + j) * LOG2_10000_OVER_256) * INV_2PI;
    }

    const int rows_per_wave = n_rows / nw;   // 512
    const int row0 = w * rows_per_wave;
    if (row0 >= n_rows) return;
    const float* tw = t + row0;
    f32x4* outw = out + (size_t)row0 * (D_MODEL / 4);

    const int nseg = rows_per_wave >> 6;     // 8 segments of 64 rows
    float tl = tw[lane];                     // segment 0: one t per lane
    for (int seg = 0; seg < nseg; ++seg) {
        const int segn = (seg + 1 < nseg) ? (seg + 1) : seg;
        const float tln = tw[segn * 64 + lane];  // prefetch next segment's t

        f32x4* sp = outw + (size_t)seg * 64 * (D_MODEL / 4);
        for (int r8 = 0; r8 < 8; ++r8) {         // 8 rows per unrolled body
#pragma unroll
            for (int j = 0; j < 8; ++j) {
                // wave-uniform broadcast of this row's t (no memory op)
                const float tv = __int_as_float(
                    __builtin_amdgcn_readlane(__float_as_int(tl), r8 * 8 + j));
                f32x4 oa, ob;
                oa.x = sin_rev(tv * fa[0]);  // even col -> sin
                oa.y = cos_rev(tv * fa[1]);  // odd col  -> cos
                oa.z = sin_rev(tv * fa[2]);
                oa.w = cos_rev(tv * fa[3]);
                ob.x = sin_rev(tv * fb[0]);
                ob.y = cos_rev(tv * fb[1]);
                ob.z = sin_rev(tv * fb[2]);
                ob.w = cos_rev(tv * fb[3]);
                f32x4* rowp = sp + (size_t)(r8 * 8 + j) * (D_MODEL / 4);
                rowp[lane] = oa;             // contiguous 1KB wave-store
                rowp[64 + lane] = ob;        // contiguous 1KB wave-store
            }
        }
        tl = tln;
    }
}

extern "C" void kernel_launch(void* const* d_in, const int* in_sizes, int n_in,
                              void* d_out, int out_size, void* d_ws, size_t ws_size,
                              hipStream_t stream) {
    const float* t = (const float*)d_in[0];
    f32x4* out = (f32x4*)d_out;
    const int n_rows = in_sizes[0];  // 524288 = 1024 waves * 512 rows
    time_embed_kernel<<<dim3(256), dim3(256), 0, stream>>>(t, out, n_rows);
}